// Round 8
// baseline (172.485 us; speedup 1.0000x reference)
//
#include <hip/hip_runtime.h>
#include <math.h>

#define DIM 64
#define KC 32
#define NPTS 32768
#define LOG_2PI 1.8378770664093453f
#define C0 (-58.0f)   // fixed logsumexp reference: logp <= -58.81 always (logdet>=0, logw<=0)
#define ST 68         // prep LDS row stride (words): mult of 4 -> 16B-aligned float4 rows/cols

typedef __attribute__((ext_vector_type(8))) short short8;
typedef __attribute__((ext_vector_type(4))) float float4v;

__device__ __forceinline__ unsigned short f2bf(float f) {
    unsigned u = __float_as_uint(f);
    u += 0x7FFFu + ((u >> 16) & 1u);   // RNE
    return (unsigned short)(u >> 16);
}

__device__ __forceinline__ float rdlane(float v, int l) {
    return __int_as_float(__builtin_amdgcn_readlane(__float_as_int(v), l));
}

// ============================================================================
// Conv: X -> bf16 + zero the accum/counter cells used by main's fused final
// reduction (runs every iteration, before main on the stream).
// ============================================================================
__global__ __launch_bounds__(256) void conv_kernel(
    const float* __restrict__ X, short* __restrict__ Xbf,
    float* __restrict__ accum, unsigned* __restrict__ counter)
{
    if (blockIdx.x == 0 && threadIdx.x == 0) {
        *accum = 0.f;
        *counter = 0u;
    }
    const int ctid = blockIdx.x * 256 + threadIdx.x;         // 0..262143
    const float4* xin = (const float4*)X + (size_t)ctid * 2; // 8 floats/thread
    float4 v0 = xin[0], v1 = xin[1];
    short8 o;
    o[0] = (short)f2bf(v0.x); o[1] = (short)f2bf(v0.y);
    o[2] = (short)f2bf(v0.z); o[3] = (short)f2bf(v0.w);
    o[4] = (short)f2bf(v1.x); o[5] = (short)f2bf(v1.y);
    o[6] = (short)f2bf(v1.z); o[7] = (short)f2bf(v1.w);
    *((short8*)Xbf + ctid) = o;
}

// ============================================================================
// Prep: 32 blocks, one per component k (r3-proven structure). 8-col blocked
// Cholesky + inverse, 8 steps, fully unrolled, per-lane streams registerized.
// Emits 8 B-fragments (aug row folded into main) + qpackN f32.
// Bpack[k]: 8 B-fragments: elem e of lane ln = B[kt*32+(ln>>4)*8+e][ct*16+(ln&15)],
//   B[j][i] = M[i][j]. cstC[k] = cst_k - C0. qpackN[k][col] = -q[col] (f32).
// ============================================================================
__global__ __launch_bounds__(256) void prep_kernel(
    const float* __restrict__ L, const float* __restrict__ mu,
    const float* __restrict__ w, short* __restrict__ Bpack,
    float* __restrict__ qpackN, float* __restrict__ cstC)
{
    const int k = blockIdx.x;
    const int t = threadIdx.x;
    const int wv = t >> 6;
    const int ln = t & 63;
    __shared__ float Llds[DIM * ST];
    __shared__ float Sig[DIM * ST];
    __shared__ float Clds[DIM * ST];
    __shared__ float Ylds[DIM * ST];   // Ylds[a*ST + b] = M[b][a]
    __shared__ float rdbuf[DIM];

    // ---- P0: load tril(L); zero C and Y (zero tails back static bounds)
    for (int idx = t; idx < DIM * DIM; idx += 256) {
        int r = idx >> 6, c = idx & 63;
        float v = L[(size_t)k * DIM * DIM + idx];
        Llds[r * ST + c] = (c <= r) ? v : 0.f;
    }
    for (int idx = t; idx < DIM * ST; idx += 256) {
        Clds[idx] = 0.f;
        Ylds[idx] = 0.f;
    }
    __syncthreads();

    // ---- P1: Sigma[ln][j]; interleaved j (j = jj*4+wv) balances triangular
    // trip counts across waves; pc = jj+1 is COMPILE-TIME after full unroll.
    {
        float Lr[DIM];
        const float4* lp = (const float4*)(Llds + ln * ST);
#pragma unroll
        for (int p = 0; p < 16; ++p) {
            float4 v = lp[p];
            Lr[4 * p] = v.x; Lr[4 * p + 1] = v.y;
            Lr[4 * p + 2] = v.z; Lr[4 * p + 3] = v.w;
        }
#pragma unroll
        for (int jj = 0; jj < 16; ++jj) {
            const int j = jj * 4 + wv;                  // wave-uniform bound
            const float4* up = (const float4*)(Llds + j * ST);
            const int pc = jj + 1;                      // == (j>>2)+1, static
            float a0 = 0.f, a1 = 0.f, a2 = 0.f, a3 = 0.f;
#pragma unroll
            for (int p = 0; p < pc; ++p) {
                float4 u = up[p];
                a0 = fmaf(Lr[4 * p], u.x, a0);
                a1 = fmaf(Lr[4 * p + 1], u.y, a1);
                a2 = fmaf(Lr[4 * p + 2], u.z, a2);
                a3 = fmaf(Lr[4 * p + 3], u.w, a3);
            }
            float s = (a0 + a1) + (a2 + a3);
            if (j == ln) s += 1.f;
            Sig[ln * ST + j] = s;
        }
    }
    __syncthreads();

    // ---- P2: 8-col blocked Cholesky + inverse, two waves, 8 steps,
    // FULLY UNROLLED; per-lane streams in registers (Cr/Yr).
    float ld2 = 0.f;   // logdet accumulator (wave 0, wave-uniform via readlane)
    {
        float Cr[DIM];   // wave0: C row ln (own lane's history, junk incl.)
        float Yr[DIM];   // wave1: M column ln (own lane's masked history)
#pragma unroll
        for (int c = 0; c < DIM; c += 8) {
            const float4* u0 = (const float4*)(Clds + (c + 0) * ST);
            const float4* u1 = (const float4*)(Clds + (c + 1) * ST);
            const float4* u2 = (const float4*)(Clds + (c + 2) * ST);
            const float4* u3 = (const float4*)(Clds + (c + 3) * ST);
            const float4* u4 = (const float4*)(Clds + (c + 4) * ST);
            const float4* u5 = (const float4*)(Clds + (c + 5) * ST);
            const float4* u6 = (const float4*)(Clds + (c + 6) * ST);
            const float4* u7 = (const float4*)(Clds + (c + 7) * ST);
            const int pc = c >> 2;           // static after unroll
            float si0 = 0.f, si1 = 0.f, si2 = 0.f, si3 = 0.f;
            float si4 = 0.f, si5 = 0.f, si6 = 0.f, si7 = 0.f;
            if (wv == 0) {
                float d0a = 0.f, d0b = 0.f, d1a = 0.f, d1b = 0.f;
                float d2a = 0.f, d2b = 0.f, d3a = 0.f, d3b = 0.f;
                float d4a = 0.f, d4b = 0.f, d5a = 0.f, d5b = 0.f;
                float d6a = 0.f, d6b = 0.f, d7a = 0.f, d7b = 0.f;
#pragma unroll
                for (int p = 0; p < pc; ++p) {
                    float crx = Cr[4 * p], cry = Cr[4 * p + 1];
                    float crz = Cr[4 * p + 2], crw = Cr[4 * p + 3];
                    float4 q0 = u0[p], q1 = u1[p], q2 = u2[p], q3 = u3[p];
                    float4 q4 = u4[p], q5 = u5[p], q6 = u6[p], q7 = u7[p];
                    d0a = fmaf(crx, q0.x, d0a); d0b = fmaf(cry, q0.y, d0b);
                    d0a = fmaf(crz, q0.z, d0a); d0b = fmaf(crw, q0.w, d0b);
                    d1a = fmaf(crx, q1.x, d1a); d1b = fmaf(cry, q1.y, d1b);
                    d1a = fmaf(crz, q1.z, d1a); d1b = fmaf(crw, q1.w, d1b);
                    d2a = fmaf(crx, q2.x, d2a); d2b = fmaf(cry, q2.y, d2b);
                    d2a = fmaf(crz, q2.z, d2a); d2b = fmaf(crw, q2.w, d2b);
                    d3a = fmaf(crx, q3.x, d3a); d3b = fmaf(cry, q3.y, d3b);
                    d3a = fmaf(crz, q3.z, d3a); d3b = fmaf(crw, q3.w, d3b);
                    d4a = fmaf(crx, q4.x, d4a); d4b = fmaf(cry, q4.y, d4b);
                    d4a = fmaf(crz, q4.z, d4a); d4b = fmaf(crw, q4.w, d4b);
                    d5a = fmaf(crx, q5.x, d5a); d5b = fmaf(cry, q5.y, d5b);
                    d5a = fmaf(crz, q5.z, d5a); d5b = fmaf(crw, q5.w, d5b);
                    d6a = fmaf(crx, q6.x, d6a); d6b = fmaf(cry, q6.y, d6b);
                    d6a = fmaf(crz, q6.z, d6a); d6b = fmaf(crw, q6.w, d6b);
                    d7a = fmaf(crx, q7.x, d7a); d7b = fmaf(cry, q7.y, d7b);
                    d7a = fmaf(crz, q7.z, d7a); d7b = fmaf(crw, q7.w, d7b);
                }
                const float4 sgA = *(const float4*)(Sig + ln * ST + c);
                const float4 sgB = *(const float4*)(Sig + ln * ST + c + 4);
                float s0 = sgA.x - (d0a + d0b);
                float s1 = sgA.y - (d1a + d1b);
                float s2 = sgA.z - (d2a + d2b);
                float s3 = sgA.w - (d3a + d3b);
                float s4 = sgB.x - (d4a + d4b);
                float s5 = sgB.y - (d5a + d5b);
                float s6 = sgB.z - (d6a + d6b);
                float s7 = sgB.w - (d7a + d7b);
                // 8x8 micro-factorization (registers + readlane)
                float dd0 = rdlane(s0, c + 0);
                float rd0 = __builtin_amdgcn_rsqf(dd0);
                float c0v = s0 * rd0;
                s1 = fmaf(-c0v, rdlane(c0v, c + 1), s1);
                s2 = fmaf(-c0v, rdlane(c0v, c + 2), s2);
                s3 = fmaf(-c0v, rdlane(c0v, c + 3), s3);
                s4 = fmaf(-c0v, rdlane(c0v, c + 4), s4);
                s5 = fmaf(-c0v, rdlane(c0v, c + 5), s5);
                s6 = fmaf(-c0v, rdlane(c0v, c + 6), s6);
                s7 = fmaf(-c0v, rdlane(c0v, c + 7), s7);
                float dd1 = rdlane(s1, c + 1);
                float rd1 = __builtin_amdgcn_rsqf(dd1);
                float c1v = s1 * rd1;
                s2 = fmaf(-c1v, rdlane(c1v, c + 2), s2);
                s3 = fmaf(-c1v, rdlane(c1v, c + 3), s3);
                s4 = fmaf(-c1v, rdlane(c1v, c + 4), s4);
                s5 = fmaf(-c1v, rdlane(c1v, c + 5), s5);
                s6 = fmaf(-c1v, rdlane(c1v, c + 6), s6);
                s7 = fmaf(-c1v, rdlane(c1v, c + 7), s7);
                float dd2 = rdlane(s2, c + 2);
                float rd2 = __builtin_amdgcn_rsqf(dd2);
                float c2v = s2 * rd2;
                s3 = fmaf(-c2v, rdlane(c2v, c + 3), s3);
                s4 = fmaf(-c2v, rdlane(c2v, c + 4), s4);
                s5 = fmaf(-c2v, rdlane(c2v, c + 5), s5);
                s6 = fmaf(-c2v, rdlane(c2v, c + 6), s6);
                s7 = fmaf(-c2v, rdlane(c2v, c + 7), s7);
                float dd3 = rdlane(s3, c + 3);
                float rd3 = __builtin_amdgcn_rsqf(dd3);
                float c3v = s3 * rd3;
                s4 = fmaf(-c3v, rdlane(c3v, c + 4), s4);
                s5 = fmaf(-c3v, rdlane(c3v, c + 5), s5);
                s6 = fmaf(-c3v, rdlane(c3v, c + 6), s6);
                s7 = fmaf(-c3v, rdlane(c3v, c + 7), s7);
                float dd4 = rdlane(s4, c + 4);
                float rd4 = __builtin_amdgcn_rsqf(dd4);
                float c4v = s4 * rd4;
                s5 = fmaf(-c4v, rdlane(c4v, c + 5), s5);
                s6 = fmaf(-c4v, rdlane(c4v, c + 6), s6);
                s7 = fmaf(-c4v, rdlane(c4v, c + 7), s7);
                float dd5 = rdlane(s5, c + 5);
                float rd5 = __builtin_amdgcn_rsqf(dd5);
                float c5v = s5 * rd5;
                s6 = fmaf(-c5v, rdlane(c5v, c + 6), s6);
                s7 = fmaf(-c5v, rdlane(c5v, c + 7), s7);
                float dd6 = rdlane(s6, c + 6);
                float rd6 = __builtin_amdgcn_rsqf(dd6);
                float c6v = s6 * rd6;
                s7 = fmaf(-c6v, rdlane(c6v, c + 7), s7);
                float dd7 = rdlane(s7, c + 7);
                float rd7 = __builtin_amdgcn_rsqf(dd7);
                float c7v = s7 * rd7;
                ld2 += ((__logf(dd0) + __logf(dd1)) + (__logf(dd2) + __logf(dd3)))
                     + ((__logf(dd4) + __logf(dd5)) + (__logf(dd6) + __logf(dd7)));
                Cr[c + 0] = c0v; Cr[c + 1] = c1v; Cr[c + 2] = c2v; Cr[c + 3] = c3v;
                Cr[c + 4] = c4v; Cr[c + 5] = c5v; Cr[c + 6] = c6v; Cr[c + 7] = c7v;
                *(float4*)(Clds + ln * ST + c)     = make_float4(c0v, c1v, c2v, c3v);
                *(float4*)(Clds + ln * ST + c + 4) = make_float4(c4v, c5v, c6v, c7v);
                if (ln == 0) {
                    *(float4*)(rdbuf + c)     = make_float4(rd0, rd1, rd2, rd3);
                    *(float4*)(rdbuf + c + 4) = make_float4(rd4, rd5, rd6, rd7);
                }
            } else if (wv == 1) {
                float e0a = 0.f, e0b = 0.f, e1a = 0.f, e1b = 0.f;
                float e2a = 0.f, e2b = 0.f, e3a = 0.f, e3b = 0.f;
                float e4a = 0.f, e4b = 0.f, e5a = 0.f, e5b = 0.f;
                float e6a = 0.f, e6b = 0.f, e7a = 0.f, e7b = 0.f;
#pragma unroll
                for (int p = 0; p < pc; ++p) {
                    float yrx = Yr[4 * p], yry = Yr[4 * p + 1];
                    float yrz = Yr[4 * p + 2], yrw = Yr[4 * p + 3];
                    float4 q0 = u0[p], q1 = u1[p], q2 = u2[p], q3 = u3[p];
                    float4 q4 = u4[p], q5 = u5[p], q6 = u6[p], q7 = u7[p];
                    e0a = fmaf(yrx, q0.x, e0a); e0b = fmaf(yry, q0.y, e0b);
                    e0a = fmaf(yrz, q0.z, e0a); e0b = fmaf(yrw, q0.w, e0b);
                    e1a = fmaf(yrx, q1.x, e1a); e1b = fmaf(yry, q1.y, e1b);
                    e1a = fmaf(yrz, q1.z, e1a); e1b = fmaf(yrw, q1.w, e1b);
                    e2a = fmaf(yrx, q2.x, e2a); e2b = fmaf(yry, q2.y, e2b);
                    e2a = fmaf(yrz, q2.z, e2a); e2b = fmaf(yrw, q2.w, e2b);
                    e3a = fmaf(yrx, q3.x, e3a); e3b = fmaf(yry, q3.y, e3b);
                    e3a = fmaf(yrz, q3.z, e3a); e3b = fmaf(yrw, q3.w, e3b);
                    e4a = fmaf(yrx, q4.x, e4a); e4b = fmaf(yry, q4.y, e4b);
                    e4a = fmaf(yrz, q4.z, e4a); e4b = fmaf(yrw, q4.w, e4b);
                    e5a = fmaf(yrx, q5.x, e5a); e5b = fmaf(yry, q5.y, e5b);
                    e5a = fmaf(yrz, q5.z, e5a); e5b = fmaf(yrw, q5.w, e5b);
                    e6a = fmaf(yrx, q6.x, e6a); e6b = fmaf(yry, q6.y, e6b);
                    e6a = fmaf(yrz, q6.z, e6a); e6b = fmaf(yrw, q6.w, e6b);
                    e7a = fmaf(yrx, q7.x, e7a); e7b = fmaf(yry, q7.y, e7b);
                    e7a = fmaf(yrz, q7.z, e7a); e7b = fmaf(yrw, q7.w, e7b);
                }
                si0 = ((ln == c + 0) ? 1.f : 0.f) - (e0a + e0b);
                si1 = ((ln == c + 1) ? 1.f : 0.f) - (e1a + e1b);
                si2 = ((ln == c + 2) ? 1.f : 0.f) - (e2a + e2b);
                si3 = ((ln == c + 3) ? 1.f : 0.f) - (e3a + e3b);
                si4 = ((ln == c + 4) ? 1.f : 0.f) - (e4a + e4b);
                si5 = ((ln == c + 5) ? 1.f : 0.f) - (e5a + e5b);
                si6 = ((ln == c + 6) ? 1.f : 0.f) - (e6a + e6b);
                si7 = ((ln == c + 7) ? 1.f : 0.f) - (e7a + e7b);
            }
            __syncthreads();   // publishes C cols c..c+7 + rdbuf[c..c+7]
            if (wv == 1) {
                const float4 rdv0 = *(const float4*)(rdbuf + c);
                const float4 rdv1 = *(const float4*)(rdbuf + c + 4);
                // broadcast b128 reads of the fresh C block (rows c+1..c+7)
                const float4 r1  = *(const float4*)(Clds + (c + 1) * ST + c);
                const float4 r2  = *(const float4*)(Clds + (c + 2) * ST + c);
                const float4 r3  = *(const float4*)(Clds + (c + 3) * ST + c);
                const float4 r4  = *(const float4*)(Clds + (c + 4) * ST + c);
                const float4 r5a = *(const float4*)(Clds + (c + 5) * ST + c);
                const float4 r5b = *(const float4*)(Clds + (c + 5) * ST + c + 4);
                const float4 r6a = *(const float4*)(Clds + (c + 6) * ST + c);
                const float4 r6b = *(const float4*)(Clds + (c + 6) * ST + c + 4);
                const float4 r7a = *(const float4*)(Clds + (c + 7) * ST + c);
                const float4 r7b = *(const float4*)(Clds + (c + 7) * ST + c + 4);
                float y0 = si0 * rdv0.x;
                float y1 = (si1 - r1.x * y0) * rdv0.y;
                float y2 = (si2 - r2.x * y0 - r2.y * y1) * rdv0.z;
                float y3 = (si3 - r3.x * y0 - r3.y * y1 - r3.z * y2) * rdv0.w;
                float y4 = (si4 - r4.x * y0 - r4.y * y1 - r4.z * y2 - r4.w * y3) * rdv1.x;
                float y5 = (si5 - r5a.x * y0 - r5a.y * y1 - r5a.z * y2 - r5a.w * y3
                                - r5b.x * y4) * rdv1.y;
                float y6 = (si6 - r6a.x * y0 - r6a.y * y1 - r6a.z * y2 - r6a.w * y3
                                - r6b.x * y4 - r6b.y * y5) * rdv1.z;
                float y7 = (si7 - r7a.x * y0 - r7a.y * y1 - r7a.z * y2 - r7a.w * y3
                                - r7b.x * y4 - r7b.y * y5 - r7b.z * y6) * rdv1.w;
                float4 yo0, yo1;
                yo0.x = (ln <= c + 0) ? y0 : 0.f;   // exact zeros above diag of M
                yo0.y = (ln <= c + 1) ? y1 : 0.f;
                yo0.z = (ln <= c + 2) ? y2 : 0.f;
                yo0.w = (ln <= c + 3) ? y3 : 0.f;
                yo1.x = (ln <= c + 4) ? y4 : 0.f;
                yo1.y = (ln <= c + 5) ? y5 : 0.f;
                yo1.z = (ln <= c + 6) ? y6 : 0.f;
                yo1.w = (ln <= c + 7) ? y7 : 0.f;
                Yr[c + 0] = yo0.x; Yr[c + 1] = yo0.y;
                Yr[c + 2] = yo0.z; Yr[c + 3] = yo0.w;
                Yr[c + 4] = yo1.x; Yr[c + 5] = yo1.y;
                Yr[c + 6] = yo1.z; Yr[c + 7] = yo1.w;
                *(float4*)(Ylds + ln * ST + c)     = yo0;   // M rows c..c+7, col ln
                *(float4*)(Ylds + ln * ST + c + 4) = yo1;
            }
        }
    }
    __syncthreads();   // Y complete

    // ---- q + cst (wave 0; ld2 is wave-uniform in wave-0 registers)
    if (wv == 0) {
        const float* muk = mu + k * DIM;
        float qv = 0.f;
#pragma unroll 8
        for (int j = 0; j < DIM; ++j)
            qv = fmaf(Ylds[j * ST + ln], muk[j], qv);   // M[ln][j]
        qpackN[k * DIM + ln] = -qv;                      // f32, negated
        // wave-parallel softmax denominator over w[0..31]
        float wl = (ln < KC) ? w[ln] : -3.0e38f;
        float wm = wl;
#pragma unroll
        for (int m = 1; m <= 32; m <<= 1)
            wm = fmaxf(wm, __shfl_xor(wm, m, 64));
        float ex = (ln < KC) ? __expf(wl - wm) : 0.f;
#pragma unroll
        for (int m = 1; m <= 32; m <<= 1)
            ex += __shfl_xor(ex, m, 64);
        if (ln == 0) {
            float logw = w[k] - (wm + __logf(ex));
            cstC[k] = -0.5f * (DIM * LOG_2PI + ld2) + logw - C0;
        }
    }
    __syncthreads();

    // ---- P3: emission (kt = 0,1 only; aug row folded into main's acc init).
    // B[j][col] = M[col][j] = Ylds[j*ST+col]
    {
        const int ct = wv;
        const int col = ct * 16 + (ln & 15);
        const int kb = (ln >> 4) * 8;
#pragma unroll
        for (int kt = 0; kt < 2; ++kt) {
            short8 v;
#pragma unroll
            for (int e = 0; e < 8; ++e)
                v[e] = (short)f2bf(Ylds[(kt * 32 + kb + e) * ST + col]);
            *(short8*)(Bpack + ((size_t)(k * 8 + ct * 2 + kt) * 64 + ln) * 8) = v;
        }
    }
}

// ============================================================================
// Main r8: r6-proven body (LDS-staged B, transposed MFMA, shfl epilogue) with
// (a) 1024 blocks x 256 rows (rr-loop: two 32-row passes/wave) — same MFMA/
// LDS totals, half the staging traffic, exactly 4 blocks/CU x 256 CU = one
// occupancy round; (b) final reduction fused via atomicAdd + last-block
// pattern (conv zeroed accum/counter; fences give release/acquire ordering).
// ============================================================================
__global__ __launch_bounds__(256, 4) void main_kernel(
    const short* __restrict__ Xbf, const float* __restrict__ Bpack,
    const float* __restrict__ qpackN, const float* __restrict__ cstC,
    float* __restrict__ accum, unsigned* __restrict__ counter,
    float* __restrict__ out)
{
    const int tid = threadIdx.x;
    const int lane = tid & 63;
    const int wv = tid >> 6;
    const int ks = blockIdx.x & 7;         // k in [4ks, 4ks+4)
    const int g = blockIdx.x >> 3;         // row group: 256 rows (0..127)

    __shared__ float4 Bsh[2048];           // 32 KB
    __shared__ float qsh[256];             // -q for the 4 comps (f32)
    {
        const float4* Bg = (const float4*)Bpack + (size_t)ks * 2048;
#pragma unroll
        for (int it = 0; it < 8; ++it)
            Bsh[it * 256 + tid] = Bg[it * 256 + tid];
        qsh[tid] = qpackN[ks * 256 + tid];
    }
    const int j8 = lane >> 4;              // 0..3 (dim block of 8)

    __syncthreads();

    const short8* Bs = (const short8*)Bsh;
    float acc = 0.f;
#pragma unroll 1
    for (int rr = 0; rr < 2; ++rr) {
        const int rbase = g * 256 + rr * 128 + wv * 32;
        const short8* xr = (const short8*)Xbf + (size_t)(rbase + (lane & 15)) * 8;
        short8 a0  = xr[j8];               // point r,    dims j8*8..
        short8 a1  = xr[j8 + 4];           // point r,    dims 32+j8*8..
        short8 b0r = xr[j8 + 128];         // point r+16 (16 rows * 8 short8)
        short8 b1r = xr[j8 + 132];
#pragma unroll
        for (int kk = 0; kk < 4; ++kk) {
            const int k = ks * 4 + kk;
            float pA = 0.f, pB = 0.f;
#pragma unroll
            for (int ct = 0; ct < 4; ++ct) {
                short8 f0 = Bs[(kk * 8 + ct * 2 + 0) * 64 + lane];
                short8 f1 = Bs[(kk * 8 + ct * 2 + 1) * 64 + lane];
                // -q[dim] init: dims ct*16 + j8*4 + i -> b128 broadcast
                const float4 nq4 = *(const float4*)(qsh + kk * 64 + ct * 16 + j8 * 4);
                float4v c0 = {nq4.x, nq4.y, nq4.z, nq4.w};
                c0 = __builtin_amdgcn_mfma_f32_16x16x32_bf16(f0, a0, c0, 0, 0, 0);
                c0 = __builtin_amdgcn_mfma_f32_16x16x32_bf16(f1, a1, c0, 0, 0, 0);
                float4v c1 = {nq4.x, nq4.y, nq4.z, nq4.w};
                c1 = __builtin_amdgcn_mfma_f32_16x16x32_bf16(f0, b0r, c1, 0, 0, 0);
                c1 = __builtin_amdgcn_mfma_f32_16x16x32_bf16(f1, b1r, c1, 0, 0, 0);
                pA = fmaf(c0[0], c0[0], pA); pA = fmaf(c0[1], c0[1], pA);
                pA = fmaf(c0[2], c0[2], pA); pA = fmaf(c0[3], c0[3], pA);
                pB = fmaf(c1[0], c1[0], pB); pB = fmaf(c1[1], c1[1], pB);
                pB = fmaf(c1[2], c1[2], pB); pB = fmaf(c1[3], c1[3], pB);
            }
            // sum the 4 lane-groups (16 dims per group) -> full maha per point
            pA += __shfl_xor(pA, 16, 64);
            pA += __shfl_xor(pA, 32, 64);
            pB += __shfl_xor(pB, 16, 64);
            pB += __shfl_xor(pB, 32, 64);
            const float cc = cstC[k];      // wave-uniform s_load
            acc += __expf(fmaf(-0.5f, pA, cc)) + __expf(fmaf(-0.5f, pB, cc));
        }
    }
    // acc depends only on lane&15 (bitwise-identical across groups):
    // sum the 16 distinct points; group duplication cancels exactly.
    acc += __shfl_xor(acc, 1, 64);
    acc += __shfl_xor(acc, 2, 64);
    acc += __shfl_xor(acc, 4, 64);
    acc += __shfl_xor(acc, 8, 64);

    __shared__ float pm[4];
    if (lane == 0) pm[wv] = acc;
    __syncthreads();
    if (tid == 0) {
        const float part = (pm[0] + pm[1]) + (pm[2] + pm[3]);
        atomicAdd(accum, part);            // device-scope by default
        __threadfence();                   // release: accum add visible first
        const unsigned old = atomicAdd(counter, 1u);
        if (old == 1023u) {                // last block: all adds visible
            __threadfence();               // acquire
            const float s = atomicAdd(accum, 0.f);   // atomic read of total
            out[0] = -(C0 + __logf(s) );
        }
    }
}

extern "C" void kernel_launch(void* const* d_in, const int* in_sizes, int n_in,
                              void* d_out, int out_size, void* d_ws, size_t ws_size,
                              hipStream_t stream) {
    const float* X  = (const float*)d_in[0];   // [32768,64]
    const float* mu = (const float*)d_in[1];   // [32,64]
    const float* L  = (const float*)d_in[2];   // [32,64,64]
    const float* w  = (const float*)d_in[3];   // [32]
    // d_in[4] = it (unused)

    char* ws = (char*)d_ws;
    short* Bpack  = (short*)ws;                        // 32*8*64*8 bf16 = 256 KB
    float* qpackN = (float*)(ws + (256 << 10));        // 32*64 f32 = 8 KB
    float* cstC   = qpackN + KC * DIM;
    float* accum  = cstC + KC;                         // 1 float
    unsigned* counter = (unsigned*)(accum + 1);        // 1 uint
    short* Xbf    = (short*)(ws + (4 << 20));          // [32768,64] bf16 = 4 MB

    conv_kernel<<<1024, 256, 0, stream>>>(X, Xbf, accum, counter);
    prep_kernel<<<KC, 256, 0, stream>>>(L, mu, w, Bpack, qpackN, cstC);
    main_kernel<<<1024, 256, 0, stream>>>(Xbf, (const float*)Bpack, qpackN, cstC,
                                          accum, counter, (float*)d_out);
}

// Round 9
// 99.678 us; speedup vs baseline: 1.7304x; 1.7304x over previous
//
#include <hip/hip_runtime.h>
#include <math.h>

#define DIM 64
#define KC 32
#define NPTS 32768
#define LOG_2PI 1.8378770664093453f
#define C0 (-58.0f)   // fixed logsumexp reference: logp <= -58.81 always (logdet>=0, logw<=0)
#define ST 68         // prep LDS row stride (words): mult of 4 -> 16B-aligned float4 rows/cols

typedef __attribute__((ext_vector_type(8))) short short8;
typedef __attribute__((ext_vector_type(4))) float float4v;

__device__ __forceinline__ unsigned short f2bf(float f) {
    unsigned u = __float_as_uint(f);
    u += 0x7FFFu + ((u >> 16) & 1u);   // RNE
    return (unsigned short)(u >> 16);
}

__device__ __forceinline__ float rdlane(float v, int l) {
    return __int_as_float(__builtin_amdgcn_readlane(__float_as_int(v), l));
}

// ============================================================================
// Conv: X -> bf16, separate dispatch. 1024 blocks x 256 thr.
// ============================================================================
__global__ __launch_bounds__(256) void conv_kernel(
    const float* __restrict__ X, short* __restrict__ Xbf)
{
    const int ctid = blockIdx.x * 256 + threadIdx.x;         // 0..262143
    const float4* xin = (const float4*)X + (size_t)ctid * 2; // 8 floats/thread
    float4 v0 = xin[0], v1 = xin[1];
    short8 o;
    o[0] = (short)f2bf(v0.x); o[1] = (short)f2bf(v0.y);
    o[2] = (short)f2bf(v0.z); o[3] = (short)f2bf(v0.w);
    o[4] = (short)f2bf(v1.x); o[5] = (short)f2bf(v1.y);
    o[6] = (short)f2bf(v1.z); o[7] = (short)f2bf(v1.w);
    *((short8*)Xbf + ctid) = o;
}

// ============================================================================
// Prep r9: Sigma PIPELINED under Cholesky. r8 post-mortem reverted the fused
// final (device-scope fences flush per-XCD L2 -> 125 MB HBM refetch). New:
// waves 2/3 (idle during P2 before) produce the 64x8 Sigma panel for step
// c+8 during step c (panel 0 in prologue). Panel cols use wave-uniform
// pcS=(cb>>2)+2 covering cols 0..j; extra terms multiply exact tril zeros
// (fmaf(x,0,a)==a) -> Sig bits identical to the r6 P1. Publication: step c's
// existing mid barrier; consumed 8 steps later. Waves 0/1 logic unchanged
// (r3-proven registerized 8-col blocked Cholesky + inverse).
// Bpack[k]: 8 B-fragments: elem e of lane ln = B[kt*32+(ln>>4)*8+e][ct*16+(ln&15)],
//   B[j][i] = M[i][j]. cstC[k] = cst_k - C0. qpackN[k][col] = -q[col] (f32).
// ============================================================================
__global__ __launch_bounds__(256) void prep_kernel(
    const float* __restrict__ L, const float* __restrict__ mu,
    const float* __restrict__ w, short* __restrict__ Bpack,
    float* __restrict__ qpackN, float* __restrict__ cstC)
{
    const int k = blockIdx.x;
    const int t = threadIdx.x;
    const int wv = t >> 6;
    const int ln = t & 63;
    __shared__ float Llds[DIM * ST];
    __shared__ float Sig[DIM * ST];
    __shared__ float Clds[DIM * ST];
    __shared__ float Ylds[DIM * ST];   // Ylds[a*ST + b] = M[b][a]
    __shared__ float rdbuf[DIM];

    // ---- P0: load tril(L); zero C and Y (zero tails back static bounds)
    for (int idx = t; idx < DIM * DIM; idx += 256) {
        int r = idx >> 6, c = idx & 63;
        float v = L[(size_t)k * DIM * DIM + idx];
        Llds[r * ST + c] = (c <= r) ? v : 0.f;
    }
    for (int idx = t; idx < DIM * ST; idx += 256) {
        Clds[idx] = 0.f;
        Ylds[idx] = 0.f;
    }
    __syncthreads();

    // ---- Sigma producers (waves 2/3): register row of L + prologue panel 0.
    float Lr[DIM];   // used only by wv >= 2
    if (wv >= 2) {
        const float4* lp = (const float4*)(Llds + ln * ST);
#pragma unroll
        for (int p = 0; p < 16; ++p) {
            float4 v = lp[p];
            Lr[4 * p] = v.x; Lr[4 * p + 1] = v.y;
            Lr[4 * p + 2] = v.z; Lr[4 * p + 3] = v.w;
        }
        const int jbase = (wv - 2) * 4;    // panel 0: cols 0..7, pcS = 2
#pragma unroll
        for (int jj = 0; jj < 4; ++jj) {
            const int j = jbase + jj;
            const float4* up = (const float4*)(Llds + j * ST);
            float a0 = 0.f, a1 = 0.f, a2 = 0.f, a3 = 0.f;
#pragma unroll
            for (int p = 0; p < 2; ++p) {
                float4 u = up[p];
                a0 = fmaf(Lr[4 * p], u.x, a0);
                a1 = fmaf(Lr[4 * p + 1], u.y, a1);
                a2 = fmaf(Lr[4 * p + 2], u.z, a2);
                a3 = fmaf(Lr[4 * p + 3], u.w, a3);
            }
            float s = (a0 + a1) + (a2 + a3);
            if (j == ln) s += 1.f;
            Sig[ln * ST + j] = s;
        }
    }
    __syncthreads();   // panel 0 visible to wave 0's step 0

    // ---- P2: 8-col blocked Cholesky + inverse, 8 steps, FULLY UNROLLED;
    // per-lane streams in registers (Cr/Yr); waves 2/3 produce panel c+8.
    float ld2 = 0.f;   // logdet accumulator (wave 0, wave-uniform via readlane)
    {
        float Cr[DIM];   // wave0: C row ln (own lane's history, junk incl.)
        float Yr[DIM];   // wave1: M column ln (own lane's masked history)
#pragma unroll
        for (int c = 0; c < DIM; c += 8) {
            const float4* u0 = (const float4*)(Clds + (c + 0) * ST);
            const float4* u1 = (const float4*)(Clds + (c + 1) * ST);
            const float4* u2 = (const float4*)(Clds + (c + 2) * ST);
            const float4* u3 = (const float4*)(Clds + (c + 3) * ST);
            const float4* u4 = (const float4*)(Clds + (c + 4) * ST);
            const float4* u5 = (const float4*)(Clds + (c + 5) * ST);
            const float4* u6 = (const float4*)(Clds + (c + 6) * ST);
            const float4* u7 = (const float4*)(Clds + (c + 7) * ST);
            const int pc = c >> 2;           // static after unroll
            float si0 = 0.f, si1 = 0.f, si2 = 0.f, si3 = 0.f;
            float si4 = 0.f, si5 = 0.f, si6 = 0.f, si7 = 0.f;
            if (wv == 0) {
                float d0a = 0.f, d0b = 0.f, d1a = 0.f, d1b = 0.f;
                float d2a = 0.f, d2b = 0.f, d3a = 0.f, d3b = 0.f;
                float d4a = 0.f, d4b = 0.f, d5a = 0.f, d5b = 0.f;
                float d6a = 0.f, d6b = 0.f, d7a = 0.f, d7b = 0.f;
#pragma unroll
                for (int p = 0; p < pc; ++p) {
                    float crx = Cr[4 * p], cry = Cr[4 * p + 1];
                    float crz = Cr[4 * p + 2], crw = Cr[4 * p + 3];
                    float4 q0 = u0[p], q1 = u1[p], q2 = u2[p], q3 = u3[p];
                    float4 q4 = u4[p], q5 = u5[p], q6 = u6[p], q7 = u7[p];
                    d0a = fmaf(crx, q0.x, d0a); d0b = fmaf(cry, q0.y, d0b);
                    d0a = fmaf(crz, q0.z, d0a); d0b = fmaf(crw, q0.w, d0b);
                    d1a = fmaf(crx, q1.x, d1a); d1b = fmaf(cry, q1.y, d1b);
                    d1a = fmaf(crz, q1.z, d1a); d1b = fmaf(crw, q1.w, d1b);
                    d2a = fmaf(crx, q2.x, d2a); d2b = fmaf(cry, q2.y, d2b);
                    d2a = fmaf(crz, q2.z, d2a); d2b = fmaf(crw, q2.w, d2b);
                    d3a = fmaf(crx, q3.x, d3a); d3b = fmaf(cry, q3.y, d3b);
                    d3a = fmaf(crz, q3.z, d3a); d3b = fmaf(crw, q3.w, d3b);
                    d4a = fmaf(crx, q4.x, d4a); d4b = fmaf(cry, q4.y, d4b);
                    d4a = fmaf(crz, q4.z, d4a); d4b = fmaf(crw, q4.w, d4b);
                    d5a = fmaf(crx, q5.x, d5a); d5b = fmaf(cry, q5.y, d5b);
                    d5a = fmaf(crz, q5.z, d5a); d5b = fmaf(crw, q5.w, d5b);
                    d6a = fmaf(crx, q6.x, d6a); d6b = fmaf(cry, q6.y, d6b);
                    d6a = fmaf(crz, q6.z, d6a); d6b = fmaf(crw, q6.w, d6b);
                    d7a = fmaf(crx, q7.x, d7a); d7b = fmaf(cry, q7.y, d7b);
                    d7a = fmaf(crz, q7.z, d7a); d7b = fmaf(crw, q7.w, d7b);
                }
                const float4 sgA = *(const float4*)(Sig + ln * ST + c);
                const float4 sgB = *(const float4*)(Sig + ln * ST + c + 4);
                float s0 = sgA.x - (d0a + d0b);
                float s1 = sgA.y - (d1a + d1b);
                float s2 = sgA.z - (d2a + d2b);
                float s3 = sgA.w - (d3a + d3b);
                float s4 = sgB.x - (d4a + d4b);
                float s5 = sgB.y - (d5a + d5b);
                float s6 = sgB.z - (d6a + d6b);
                float s7 = sgB.w - (d7a + d7b);
                // 8x8 micro-factorization (registers + readlane)
                float dd0 = rdlane(s0, c + 0);
                float rd0 = __builtin_amdgcn_rsqf(dd0);
                float c0v = s0 * rd0;
                s1 = fmaf(-c0v, rdlane(c0v, c + 1), s1);
                s2 = fmaf(-c0v, rdlane(c0v, c + 2), s2);
                s3 = fmaf(-c0v, rdlane(c0v, c + 3), s3);
                s4 = fmaf(-c0v, rdlane(c0v, c + 4), s4);
                s5 = fmaf(-c0v, rdlane(c0v, c + 5), s5);
                s6 = fmaf(-c0v, rdlane(c0v, c + 6), s6);
                s7 = fmaf(-c0v, rdlane(c0v, c + 7), s7);
                float dd1 = rdlane(s1, c + 1);
                float rd1 = __builtin_amdgcn_rsqf(dd1);
                float c1v = s1 * rd1;
                s2 = fmaf(-c1v, rdlane(c1v, c + 2), s2);
                s3 = fmaf(-c1v, rdlane(c1v, c + 3), s3);
                s4 = fmaf(-c1v, rdlane(c1v, c + 4), s4);
                s5 = fmaf(-c1v, rdlane(c1v, c + 5), s5);
                s6 = fmaf(-c1v, rdlane(c1v, c + 6), s6);
                s7 = fmaf(-c1v, rdlane(c1v, c + 7), s7);
                float dd2 = rdlane(s2, c + 2);
                float rd2 = __builtin_amdgcn_rsqf(dd2);
                float c2v = s2 * rd2;
                s3 = fmaf(-c2v, rdlane(c2v, c + 3), s3);
                s4 = fmaf(-c2v, rdlane(c2v, c + 4), s4);
                s5 = fmaf(-c2v, rdlane(c2v, c + 5), s5);
                s6 = fmaf(-c2v, rdlane(c2v, c + 6), s6);
                s7 = fmaf(-c2v, rdlane(c2v, c + 7), s7);
                float dd3 = rdlane(s3, c + 3);
                float rd3 = __builtin_amdgcn_rsqf(dd3);
                float c3v = s3 * rd3;
                s4 = fmaf(-c3v, rdlane(c3v, c + 4), s4);
                s5 = fmaf(-c3v, rdlane(c3v, c + 5), s5);
                s6 = fmaf(-c3v, rdlane(c3v, c + 6), s6);
                s7 = fmaf(-c3v, rdlane(c3v, c + 7), s7);
                float dd4 = rdlane(s4, c + 4);
                float rd4 = __builtin_amdgcn_rsqf(dd4);
                float c4v = s4 * rd4;
                s5 = fmaf(-c4v, rdlane(c4v, c + 5), s5);
                s6 = fmaf(-c4v, rdlane(c4v, c + 6), s6);
                s7 = fmaf(-c4v, rdlane(c4v, c + 7), s7);
                float dd5 = rdlane(s5, c + 5);
                float rd5 = __builtin_amdgcn_rsqf(dd5);
                float c5v = s5 * rd5;
                s6 = fmaf(-c5v, rdlane(c5v, c + 6), s6);
                s7 = fmaf(-c5v, rdlane(c5v, c + 7), s7);
                float dd6 = rdlane(s6, c + 6);
                float rd6 = __builtin_amdgcn_rsqf(dd6);
                float c6v = s6 * rd6;
                s7 = fmaf(-c6v, rdlane(c6v, c + 7), s7);
                float dd7 = rdlane(s7, c + 7);
                float rd7 = __builtin_amdgcn_rsqf(dd7);
                float c7v = s7 * rd7;
                ld2 += ((__logf(dd0) + __logf(dd1)) + (__logf(dd2) + __logf(dd3)))
                     + ((__logf(dd4) + __logf(dd5)) + (__logf(dd6) + __logf(dd7)));
                Cr[c + 0] = c0v; Cr[c + 1] = c1v; Cr[c + 2] = c2v; Cr[c + 3] = c3v;
                Cr[c + 4] = c4v; Cr[c + 5] = c5v; Cr[c + 6] = c6v; Cr[c + 7] = c7v;
                *(float4*)(Clds + ln * ST + c)     = make_float4(c0v, c1v, c2v, c3v);
                *(float4*)(Clds + ln * ST + c + 4) = make_float4(c4v, c5v, c6v, c7v);
                if (ln == 0) {
                    *(float4*)(rdbuf + c)     = make_float4(rd0, rd1, rd2, rd3);
                    *(float4*)(rdbuf + c + 4) = make_float4(rd4, rd5, rd6, rd7);
                }
            } else if (wv == 1) {
                float e0a = 0.f, e0b = 0.f, e1a = 0.f, e1b = 0.f;
                float e2a = 0.f, e2b = 0.f, e3a = 0.f, e3b = 0.f;
                float e4a = 0.f, e4b = 0.f, e5a = 0.f, e5b = 0.f;
                float e6a = 0.f, e6b = 0.f, e7a = 0.f, e7b = 0.f;
#pragma unroll
                for (int p = 0; p < pc; ++p) {
                    float yrx = Yr[4 * p], yry = Yr[4 * p + 1];
                    float yrz = Yr[4 * p + 2], yrw = Yr[4 * p + 3];
                    float4 q0 = u0[p], q1 = u1[p], q2 = u2[p], q3 = u3[p];
                    float4 q4 = u4[p], q5 = u5[p], q6 = u6[p], q7 = u7[p];
                    e0a = fmaf(yrx, q0.x, e0a); e0b = fmaf(yry, q0.y, e0b);
                    e0a = fmaf(yrz, q0.z, e0a); e0b = fmaf(yrw, q0.w, e0b);
                    e1a = fmaf(yrx, q1.x, e1a); e1b = fmaf(yry, q1.y, e1b);
                    e1a = fmaf(yrz, q1.z, e1a); e1b = fmaf(yrw, q1.w, e1b);
                    e2a = fmaf(yrx, q2.x, e2a); e2b = fmaf(yry, q2.y, e2b);
                    e2a = fmaf(yrz, q2.z, e2a); e2b = fmaf(yrw, q2.w, e2b);
                    e3a = fmaf(yrx, q3.x, e3a); e3b = fmaf(yry, q3.y, e3b);
                    e3a = fmaf(yrz, q3.z, e3a); e3b = fmaf(yrw, q3.w, e3b);
                    e4a = fmaf(yrx, q4.x, e4a); e4b = fmaf(yry, q4.y, e4b);
                    e4a = fmaf(yrz, q4.z, e4a); e4b = fmaf(yrw, q4.w, e4b);
                    e5a = fmaf(yrx, q5.x, e5a); e5b = fmaf(yry, q5.y, e5b);
                    e5a = fmaf(yrz, q5.z, e5a); e5b = fmaf(yrw, q5.w, e5b);
                    e6a = fmaf(yrx, q6.x, e6a); e6b = fmaf(yry, q6.y, e6b);
                    e6a = fmaf(yrz, q6.z, e6a); e6b = fmaf(yrw, q6.w, e6b);
                    e7a = fmaf(yrx, q7.x, e7a); e7b = fmaf(yry, q7.y, e7b);
                    e7a = fmaf(yrz, q7.z, e7a); e7b = fmaf(yrw, q7.w, e7b);
                }
                si0 = ((ln == c + 0) ? 1.f : 0.f) - (e0a + e0b);
                si1 = ((ln == c + 1) ? 1.f : 0.f) - (e1a + e1b);
                si2 = ((ln == c + 2) ? 1.f : 0.f) - (e2a + e2b);
                si3 = ((ln == c + 3) ? 1.f : 0.f) - (e3a + e3b);
                si4 = ((ln == c + 4) ? 1.f : 0.f) - (e4a + e4b);
                si5 = ((ln == c + 5) ? 1.f : 0.f) - (e5a + e5b);
                si6 = ((ln == c + 6) ? 1.f : 0.f) - (e6a + e6b);
                si7 = ((ln == c + 7) ? 1.f : 0.f) - (e7a + e7b);
            } else if (c < DIM - 8) {
                // ---- Sigma panel for step c+8 (cols c+8..c+15), waves 2/3.
                // pcS covers cols 0..(c+15); extra cols multiply exact tril
                // zeros of row j -> Sig bits identical to the r6 P1.
                const int cb = c + 8;
                const int jbase = cb + (wv - 2) * 4;
                const int pcS = (cb >> 2) + 2;   // static after unroll
#pragma unroll
                for (int jj = 0; jj < 4; ++jj) {
                    const int j = jbase + jj;
                    const float4* up = (const float4*)(Llds + j * ST);
                    float a0 = 0.f, a1 = 0.f, a2 = 0.f, a3 = 0.f;
#pragma unroll
                    for (int p = 0; p < pcS; ++p) {
                        float4 u = up[p];
                        a0 = fmaf(Lr[4 * p], u.x, a0);
                        a1 = fmaf(Lr[4 * p + 1], u.y, a1);
                        a2 = fmaf(Lr[4 * p + 2], u.z, a2);
                        a3 = fmaf(Lr[4 * p + 3], u.w, a3);
                    }
                    float s = (a0 + a1) + (a2 + a3);
                    if (j == ln) s += 1.f;
                    Sig[ln * ST + j] = s;
                }
            }
            __syncthreads();   // publishes C cols c..c+7 + rdbuf + Sig panel c+8
            if (wv == 1) {
                const float4 rdv0 = *(const float4*)(rdbuf + c);
                const float4 rdv1 = *(const float4*)(rdbuf + c + 4);
                // broadcast b128 reads of the fresh C block (rows c+1..c+7)
                const float4 r1  = *(const float4*)(Clds + (c + 1) * ST + c);
                const float4 r2  = *(const float4*)(Clds + (c + 2) * ST + c);
                const float4 r3  = *(const float4*)(Clds + (c + 3) * ST + c);
                const float4 r4  = *(const float4*)(Clds + (c + 4) * ST + c);
                const float4 r5a = *(const float4*)(Clds + (c + 5) * ST + c);
                const float4 r5b = *(const float4*)(Clds + (c + 5) * ST + c + 4);
                const float4 r6a = *(const float4*)(Clds + (c + 6) * ST + c);
                const float4 r6b = *(const float4*)(Clds + (c + 6) * ST + c + 4);
                const float4 r7a = *(const float4*)(Clds + (c + 7) * ST + c);
                const float4 r7b = *(const float4*)(Clds + (c + 7) * ST + c + 4);
                float y0 = si0 * rdv0.x;
                float y1 = (si1 - r1.x * y0) * rdv0.y;
                float y2 = (si2 - r2.x * y0 - r2.y * y1) * rdv0.z;
                float y3 = (si3 - r3.x * y0 - r3.y * y1 - r3.z * y2) * rdv0.w;
                float y4 = (si4 - r4.x * y0 - r4.y * y1 - r4.z * y2 - r4.w * y3) * rdv1.x;
                float y5 = (si5 - r5a.x * y0 - r5a.y * y1 - r5a.z * y2 - r5a.w * y3
                                - r5b.x * y4) * rdv1.y;
                float y6 = (si6 - r6a.x * y0 - r6a.y * y1 - r6a.z * y2 - r6a.w * y3
                                - r6b.x * y4 - r6b.y * y5) * rdv1.z;
                float y7 = (si7 - r7a.x * y0 - r7a.y * y1 - r7a.z * y2 - r7a.w * y3
                                - r7b.x * y4 - r7b.y * y5 - r7b.z * y6) * rdv1.w;
                float4 yo0, yo1;
                yo0.x = (ln <= c + 0) ? y0 : 0.f;   // exact zeros above diag of M
                yo0.y = (ln <= c + 1) ? y1 : 0.f;
                yo0.z = (ln <= c + 2) ? y2 : 0.f;
                yo0.w = (ln <= c + 3) ? y3 : 0.f;
                yo1.x = (ln <= c + 4) ? y4 : 0.f;
                yo1.y = (ln <= c + 5) ? y5 : 0.f;
                yo1.z = (ln <= c + 6) ? y6 : 0.f;
                yo1.w = (ln <= c + 7) ? y7 : 0.f;
                Yr[c + 0] = yo0.x; Yr[c + 1] = yo0.y;
                Yr[c + 2] = yo0.z; Yr[c + 3] = yo0.w;
                Yr[c + 4] = yo1.x; Yr[c + 5] = yo1.y;
                Yr[c + 6] = yo1.z; Yr[c + 7] = yo1.w;
                *(float4*)(Ylds + ln * ST + c)     = yo0;   // M rows c..c+7, col ln
                *(float4*)(Ylds + ln * ST + c + 4) = yo1;
            }
        }
    }
    __syncthreads();   // Y complete

    // ---- q + cst (wave 0; ld2 is wave-uniform in wave-0 registers)
    if (wv == 0) {
        const float* muk = mu + k * DIM;
        float qv = 0.f;
#pragma unroll 8
        for (int j = 0; j < DIM; ++j)
            qv = fmaf(Ylds[j * ST + ln], muk[j], qv);   // M[ln][j]
        qpackN[k * DIM + ln] = -qv;                      // f32, negated
        // wave-parallel softmax denominator over w[0..31]
        float wl = (ln < KC) ? w[ln] : -3.0e38f;
        float wm = wl;
#pragma unroll
        for (int m = 1; m <= 32; m <<= 1)
            wm = fmaxf(wm, __shfl_xor(wm, m, 64));
        float ex = (ln < KC) ? __expf(wl - wm) : 0.f;
#pragma unroll
        for (int m = 1; m <= 32; m <<= 1)
            ex += __shfl_xor(ex, m, 64);
        if (ln == 0) {
            float logw = w[k] - (wm + __logf(ex));
            cstC[k] = -0.5f * (DIM * LOG_2PI + ld2) + logw - C0;
        }
    }
    __syncthreads();

    // ---- P3: emission (kt = 0,1 only; aug row folded into main's acc init).
    // B[j][col] = M[col][j] = Ylds[j*ST+col]
    {
        const int ct = wv;
        const int col = ct * 16 + (ln & 15);
        const int kb = (ln >> 4) * 8;
#pragma unroll
        for (int kt = 0; kt < 2; ++kt) {
            short8 v;
#pragma unroll
            for (int e = 0; e < 8; ++e)
                v[e] = (short)f2bf(Ylds[(kt * 32 + kb + e) * ST + col]);
            *(short8*)(Bpack + ((size_t)(k * 8 + ct * 2 + kt) * 64 + ln) * 8) = v;
        }
    }
}

// ============================================================================
// Main: r6 verbatim (measured best, 99.9 total): LDS-staged B (32 KB),
// transposed MFMA (C rows = dims, cols = points), maha = 16 in-reg squares +
// 2 shfl_xor, block reduce = 4 shfl + lane0; 2048 blocks; 4 blocks/CU.
// ============================================================================
__global__ __launch_bounds__(256, 4) void main_kernel(
    const short* __restrict__ Xbf, const float* __restrict__ Bpack,
    const float* __restrict__ qpackN, const float* __restrict__ cstC,
    float* __restrict__ partials)
{
    const int tid = threadIdx.x;
    const int lane = tid & 63;
    const int wv = tid >> 6;
    const int ks = blockIdx.x & 7;         // k in [4ks, 4ks+4)
    const int g = blockIdx.x >> 3;         // row group: 128 rows

    __shared__ float4 Bsh[2048];           // 32 KB
    __shared__ float qsh[256];             // -q for the 4 comps (f32)
    {
        const float4* Bg = (const float4*)Bpack + (size_t)ks * 2048;
#pragma unroll
        for (int it = 0; it < 8; ++it)
            Bsh[it * 256 + tid] = Bg[it * 256 + tid];
        qsh[tid] = qpackN[ks * 256 + tid];
    }

    const int rbase = g * 128 + wv * 32;
    const int j8 = lane >> 4;              // 0..3 (dim block of 8)
    const short8* xr = (const short8*)Xbf + (size_t)(rbase + (lane & 15)) * 8;
    short8 a0  = xr[j8];                   // point r,    dims j8*8..
    short8 a1  = xr[j8 + 4];               // point r,    dims 32+j8*8..
    short8 b0r = xr[j8 + 128];             // point r+16 (16 rows * 8 short8)
    short8 b1r = xr[j8 + 132];

    __syncthreads();

    const short8* Bs = (const short8*)Bsh;
    float acc = 0.f;
#pragma unroll
    for (int kk = 0; kk < 4; ++kk) {
        const int k = ks * 4 + kk;
        float pA = 0.f, pB = 0.f;
#pragma unroll
        for (int ct = 0; ct < 4; ++ct) {
            short8 f0 = Bs[(kk * 8 + ct * 2 + 0) * 64 + lane];
            short8 f1 = Bs[(kk * 8 + ct * 2 + 1) * 64 + lane];
            // -q[dim] init: dims ct*16 + j8*4 + i -> one b128 broadcast
            const float4 nq4 = *(const float4*)(qsh + kk * 64 + ct * 16 + j8 * 4);
            float4v c0 = {nq4.x, nq4.y, nq4.z, nq4.w};
            c0 = __builtin_amdgcn_mfma_f32_16x16x32_bf16(f0, a0, c0, 0, 0, 0);
            c0 = __builtin_amdgcn_mfma_f32_16x16x32_bf16(f1, a1, c0, 0, 0, 0);
            float4v c1 = {nq4.x, nq4.y, nq4.z, nq4.w};
            c1 = __builtin_amdgcn_mfma_f32_16x16x32_bf16(f0, b0r, c1, 0, 0, 0);
            c1 = __builtin_amdgcn_mfma_f32_16x16x32_bf16(f1, b1r, c1, 0, 0, 0);
            pA = fmaf(c0[0], c0[0], pA); pA = fmaf(c0[1], c0[1], pA);
            pA = fmaf(c0[2], c0[2], pA); pA = fmaf(c0[3], c0[3], pA);
            pB = fmaf(c1[0], c1[0], pB); pB = fmaf(c1[1], c1[1], pB);
            pB = fmaf(c1[2], c1[2], pB); pB = fmaf(c1[3], c1[3], pB);
        }
        // sum the 4 lane-groups (16 dims per group) -> full maha per point
        pA += __shfl_xor(pA, 16, 64);
        pA += __shfl_xor(pA, 32, 64);
        pB += __shfl_xor(pB, 16, 64);
        pB += __shfl_xor(pB, 32, 64);
        const float cc = cstC[k];          // wave-uniform s_load
        acc += __expf(fmaf(-0.5f, pA, cc)) + __expf(fmaf(-0.5f, pB, cc));
    }
    // acc depends only on lane&15 (bitwise-identical across groups):
    // sum the 16 distinct points; group duplication cancels exactly.
    acc += __shfl_xor(acc, 1, 64);
    acc += __shfl_xor(acc, 2, 64);
    acc += __shfl_xor(acc, 4, 64);
    acc += __shfl_xor(acc, 8, 64);

    __shared__ float pm[4];
    if (lane == 0) pm[wv] = acc;
    __syncthreads();
    if (tid == 0)
        partials[blockIdx.x] = (pm[0] + pm[1]) + (pm[2] + pm[3]);
}

// ============================================================================
// Final: sum 2048 partials -> out = -(C0 + log(S))
// ============================================================================
__global__ __launch_bounds__(256) void final_kernel(
    const float* __restrict__ partials, int n, float* __restrict__ out)
{
    const int tid = threadIdx.x;
    float s = 0.f;
    for (int i = tid; i < n; i += 256) s += partials[i];
#pragma unroll
    for (int m = 1; m <= 32; m <<= 1) s += __shfl_xor(s, m, 64);
    __shared__ float pm[4];
    if ((tid & 63) == 0) pm[tid >> 6] = s;
    __syncthreads();
    if (tid == 0) out[0] = -(C0 + logf((pm[0] + pm[1]) + (pm[2] + pm[3])));
}

extern "C" void kernel_launch(void* const* d_in, const int* in_sizes, int n_in,
                              void* d_out, int out_size, void* d_ws, size_t ws_size,
                              hipStream_t stream) {
    const float* X  = (const float*)d_in[0];   // [32768,64]
    const float* mu = (const float*)d_in[1];   // [32,64]
    const float* L  = (const float*)d_in[2];   // [32,64,64]
    const float* w  = (const float*)d_in[3];   // [32]
    // d_in[4] = it (unused)

    char* ws = (char*)d_ws;
    short* Bpack  = (short*)ws;                        // 32*8*64*8 bf16 = 256 KB
    float* qpackN = (float*)(ws + (256 << 10));        // 32*64 f32 = 8 KB
    float* cstC   = qpackN + KC * DIM;
    float* parts  = cstC + KC;                         // 2048 floats
    short* Xbf    = (short*)(ws + (4 << 20));          // [32768,64] bf16 = 4 MB

    conv_kernel<<<1024, 256, 0, stream>>>(X, Xbf);
    prep_kernel<<<KC, 256, 0, stream>>>(L, mu, w, Bpack, qpackN, cstC);
    main_kernel<<<2048, 256, 0, stream>>>(Xbf, (const float*)Bpack, qpackN, cstC, parts);
    final_kernel<<<1, 256, 0, stream>>>(parts, 2048, (float*)d_out);
}